// Round 14
// baseline (2008.413 us; speedup 1.0000x reference)
//
#include <hip/hip_runtime.h>

#define NN 50000
#define MPAD 50176  // 392 * 128
#define DD 512
#define NE 150000

typedef float f32x2 __attribute__((ext_vector_type(2)));
typedef float f32x4 __attribute__((ext_vector_type(4)));
typedef float f32x8 __attribute__((ext_vector_type(8)));
typedef __bf16 bf16x8 __attribute__((ext_vector_type(8)));
typedef unsigned short u16x8 __attribute__((ext_vector_type(8)));
typedef unsigned int u32x2 __attribute__((ext_vector_type(2)));

__device__ __forceinline__ void gload16(const void* g, void* l) {
  __builtin_amdgcn_global_load_lds((const __attribute__((address_space(1))) void*)g,
                                   (__attribute__((address_space(3))) void*)l, 16, 0, 0);
}

// ---- fp8 e4m3 pack/unpack (storage-only quantization) ----
__device__ __forceinline__ u32x2 f32x8_to_fp8(f32x8 v) {
  int t0 = __builtin_amdgcn_cvt_pk_fp8_f32(v[0], v[1], 0, false);
  t0 = __builtin_amdgcn_cvt_pk_fp8_f32(v[2], v[3], t0, true);
  int t1 = __builtin_amdgcn_cvt_pk_fp8_f32(v[4], v[5], 0, false);
  t1 = __builtin_amdgcn_cvt_pk_fp8_f32(v[6], v[7], t1, true);
  u32x2 r;
  r[0] = (unsigned)t0;
  r[1] = (unsigned)t1;
  return r;
}
__device__ __forceinline__ f32x8 fp8x8_to_f32(u32x2 u) {
  f32x2 a = __builtin_amdgcn_cvt_pk_f32_fp8((int)u[0], false);
  f32x2 b = __builtin_amdgcn_cvt_pk_f32_fp8((int)u[0], true);
  f32x2 c = __builtin_amdgcn_cvt_pk_f32_fp8((int)u[1], false);
  f32x2 d = __builtin_amdgcn_cvt_pk_f32_fp8((int)u[1], true);
  f32x8 v;
  v[0]=a[0]; v[1]=a[1]; v[2]=b[0]; v[3]=b[1]; v[4]=c[0]; v[5]=c[1]; v[6]=d[0]; v[7]=d[1];
  return v;
}

// ============ prep1: x->fp8 (12500) | W1_0->bf16 (128) | edge count (586) |
//              xact pad zero (44) | statsL/cs/done zero (1).  Grid = 13259.
__global__ __launch_bounds__(256) void prep1_k(
    const float* __restrict__ x, const float* __restrict__ W1,
    const int* __restrict__ dst, unsigned char* __restrict__ xq,
    unsigned short* __restrict__ wb1, int* __restrict__ cnt,
    unsigned short* __restrict__ xact, float* __restrict__ statsL,
    float* __restrict__ cs2, float* __restrict__ cs3, int* __restrict__ doneL) {
  const int b = blockIdx.x;
  const int tid = threadIdx.x;
  if (b < 12500) {  // x f32 -> fp8
    const size_t i = ((size_t)b * 256 + tid) * 8;
    const f32x4* g = reinterpret_cast<const f32x4*>(x + i);
    f32x4 a = g[0], c = g[1];
    f32x8 v;
    v[0]=a[0]; v[1]=a[1]; v[2]=a[2]; v[3]=a[3]; v[4]=c[0]; v[5]=c[1]; v[6]=c[2]; v[7]=c[3];
    *reinterpret_cast<u32x2*>(xq + i) = f32x8_to_fp8(v);
  } else if (b < 12628) {  // W1 layer 0 -> bf16
    const size_t i = ((size_t)(b - 12500) * 256 + tid) * 8;
    const f32x4* g = reinterpret_cast<const f32x4*>(W1 + i);
    f32x4 a = g[0], c = g[1];
    f32x8 v;
    v[0]=a[0]; v[1]=a[1]; v[2]=a[2]; v[3]=a[3]; v[4]=c[0]; v[5]=c[1]; v[6]=c[2]; v[7]=c[3];
    *reinterpret_cast<bf16x8*>(wb1 + i) = __builtin_convertvector(v, bf16x8);
  } else if (b < 13214) {  // in-degree count (cursor pre-zeroed by memset)
    const int e = (b - 12628) * 256 + tid;
    if (e < NE) atomicAdd(&cnt[dst[e]], 1);
  } else if (b < 13258) {  // xact pad rows -> 0
    const int i = (b - 13214) * 256 + tid;
    u16x8 zz = {};
    *reinterpret_cast<u16x8*>(xact + (size_t)NN * DD + (size_t)i * 8) = zz;
  } else {  // zero statsL (4 layers) + colsum accumulators + done counters
    for (int i = tid; i < 8 * DD; i += 256) statsL[i] = 0.f;
    for (int i = tid; i < DD; i += 256) {
      cs2[i] = 0.f;
      cs3[i] = 0.f;
    }
    if (tid < 4) doneL[tid] = 0;
  }
}

// ============ single-block exclusive scan ============
__global__ __launch_bounds__(1024) void scan_k(const int* __restrict__ cnt,
                                               int* __restrict__ rowptr,
                                               int* __restrict__ cursor) {
  __shared__ int wsum[16];
  __shared__ int base_s;
  if (threadIdx.x == 0) base_s = 0;
  __syncthreads();
  const int lane = threadIdx.x & 63;
  const int wid = threadIdx.x >> 6;
  for (int c0 = 0; c0 < NN; c0 += 1024) {
    const int i = c0 + threadIdx.x;
    const int v = (i < NN) ? cnt[i] : 0;
    int incl = v;
#pragma unroll
    for (int d = 1; d < 64; d <<= 1) {
      int t = __shfl_up(incl, d);
      if (lane >= d) incl += t;
    }
    if (lane == 63) wsum[wid] = incl;
    __syncthreads();
    if (wid == 0 && lane < 16) {
      int wv = wsum[lane];
#pragma unroll
      for (int d = 1; d < 16; d <<= 1) {
        int t = __shfl_up(wv, d);
        if (lane >= d) wv += t;
      }
      wsum[lane] = wv;
    }
    __syncthreads();
    const int waveoff = wid ? wsum[wid - 1] : 0;
    const int excl = base_s + waveoff + incl - v;
    if (i < NN) {
      rowptr[i] = excl;
      cursor[i] = excl;
    }
    __syncthreads();
    if (threadIdx.x == 0) base_s += wsum[15];
    __syncthreads();
  }
  if (threadIdx.x == 0) rowptr[NN] = base_s;
}

// ============ prep2: CSR fill (586) | W2 transpose (192).  Grid = 778. ============
__global__ __launch_bounds__(256) void prep2_k(
    const int* __restrict__ src, const int* __restrict__ dst,
    int* __restrict__ cursor, int* __restrict__ csrc,
    const float* __restrict__ W2, float* __restrict__ W2T) {
  __shared__ float t[64][65];
  const int b = blockIdx.x;
  const int tid = threadIdx.x;
  if (b < 586) {
    const int e = b * 256 + tid;
    if (e < NE) {
      const int pos = atomicAdd(&cursor[dst[e]], 1);
      csrc[pos] = src[e];
    }
  } else {
    const int q = b - 586;
    const int l = q >> 6;
    const int rem = q & 63;
    const int a0 = (rem >> 3) * 64;
    const int b0 = (rem & 7) * 64;
    const float* sp = W2 + (size_t)l * DD * DD;
    float* dp = W2T + (size_t)l * DD * DD;
#pragma unroll
    for (int k = 0; k < 16; ++k) {
      const int idx = k * 256 + tid;
      const int r = idx >> 6, c = idx & 63;
      t[r][c] = sp[(size_t)(a0 + r) * DD + b0 + c];
    }
    __syncthreads();
#pragma unroll
    for (int k = 0; k < 16; ++k) {
      const int idx = k * 256 + tid;
      const int r = idx >> 6, c = idx & 63;
      dp[(size_t)(b0 + r) * DD + a0 + c] = t[c][r];
    }
  }
}

// ============ prep3: Wf (48) | cvec (3) | degp1 (196).  Grid = 247. ============
__global__ __launch_bounds__(256) void prep3_k(
    const float* __restrict__ W1all, const float* __restrict__ W2T,
    unsigned short* __restrict__ WF, const float* __restrict__ b2all,
    float* __restrict__ cvec, const int* __restrict__ rowptr,
    float* __restrict__ degp1) {
  __shared__ char pl[36864];
  const int b = blockIdx.x;
  const int tid = threadIdx.x;
  if (b < 48) {
    constexpr int LDK = 72;
    unsigned short* lA = (unsigned short*)pl;
    unsigned short* lB = (unsigned short*)(pl + 18432);
    const int l = b >> 4;
    const int rem = b & 15;
    const int brow = (rem >> 2) * 128;
    const int bcol = (rem & 3) * 128;
    const float* A = W1all + (size_t)(l + 1) * DD * DD;
    const float* Bt = W2T + (size_t)l * DD * DD;
    unsigned short* out = WF + (size_t)l * DD * DD;
    const int lane = tid & 63;
    const int w = tid >> 6;
    const int wr = (w >> 1) * 64;
    const int wc = (w & 1) * 64;
    const int fr = lane & 15;
    const int fg = lane >> 4;
    f32x4 acc[4][4] = {};
    const int srow = tid >> 3;
    const int scol = (tid & 7) * 8;
    for (int kt = 0; kt < 8; ++kt) {
      const int k0 = kt * 64 + scol;
      __syncthreads();
#pragma unroll
      for (int p = 0; p < 4; ++p) {
        const int r = srow + 32 * p;
        {
          const f32x4* g = reinterpret_cast<const f32x4*>(A + (size_t)(brow + r) * DD + k0);
          f32x4 v0 = g[0], v1 = g[1];
          f32x8 vf;
          vf[0]=v0[0]; vf[1]=v0[1]; vf[2]=v0[2]; vf[3]=v0[3];
          vf[4]=v1[0]; vf[5]=v1[1]; vf[6]=v1[2]; vf[7]=v1[3];
          *reinterpret_cast<bf16x8*>(&lA[r * LDK + scol]) = __builtin_convertvector(vf, bf16x8);
        }
        {
          const f32x4* g = reinterpret_cast<const f32x4*>(Bt + (size_t)(bcol + r) * DD + k0);
          f32x4 v0 = g[0], v1 = g[1];
          f32x8 vf;
          vf[0]=v0[0]; vf[1]=v0[1]; vf[2]=v0[2]; vf[3]=v0[3];
          vf[4]=v1[0]; vf[5]=v1[1]; vf[6]=v1[2]; vf[7]=v1[3];
          *reinterpret_cast<bf16x8*>(&lB[r * LDK + scol]) = __builtin_convertvector(vf, bf16x8);
        }
      }
      __syncthreads();
#pragma unroll
      for (int kk = 0; kk < 2; ++kk) {
        bf16x8 av[4], bv[4];
#pragma unroll
        for (int i = 0; i < 4; ++i)
          av[i] = *reinterpret_cast<const bf16x8*>(&lA[(wr + i * 16 + fr) * LDK + kk * 32 + fg * 8]);
#pragma unroll
        for (int j = 0; j < 4; ++j)
          bv[j] = *reinterpret_cast<const bf16x8*>(&lB[(wc + j * 16 + fr) * LDK + kk * 32 + fg * 8]);
#pragma unroll
        for (int i = 0; i < 4; ++i)
#pragma unroll
          for (int j = 0; j < 4; ++j)
            acc[i][j] = __builtin_amdgcn_mfma_f32_16x16x32_bf16(av[i], bv[j], acc[i][j], 0, 0, 0);
      }
    }
#pragma unroll
    for (int j = 0; j < 4; ++j) {
      const int col = bcol + wc + j * 16 + fr;
#pragma unroll
      for (int i = 0; i < 4; ++i) {
        const int rb = brow + wr + i * 16 + fg * 4;
#pragma unroll
        for (int r = 0; r < 4; ++r) {
          __bf16 bb = (__bf16)acc[i][j][r];
          out[(size_t)(rb + r) * DD + col] = __builtin_bit_cast(unsigned short, bb);
        }
      }
    }
  } else if (b < 51) {
    const int l = b - 48;
    float* bb = (float*)pl;
    bb[tid] = b2all[(size_t)l * DD + tid];
    bb[tid + 256] = b2all[(size_t)l * DD + tid + 256];
    __syncthreads();
#pragma unroll
    for (int rep = 0; rep < 2; ++rep) {
      const int n = tid + rep * 256;
      const float* row = W1all + (size_t)(l + 1) * DD * DD + (size_t)n * DD;
      float s = 0.f;
      for (int a = 0; a < DD; a += 4) {
        f32x4 v = *reinterpret_cast<const f32x4*>(row + a);
        s += v[0] * bb[a] + v[1] * bb[a + 1] + v[2] * bb[a + 2] + v[3] * bb[a + 3];
      }
      cvec[l * DD + n] = s;
    }
  } else {
    const int i = (b - 51) * 256 + tid;
    if (i < MPAD) degp1[i] = (i < NN) ? (float)(1 + rowptr[i + 1] - rowptr[i]) : 0.f;
  }
}

// ============ layer-0 aggregation from fp8 x (unroll-2) ============
__global__ __launch_bounds__(256) void agg_x_k(const unsigned char* __restrict__ xq,
                                               const int* __restrict__ rowptr,
                                               const int* __restrict__ csrc,
                                               unsigned short* __restrict__ xout) {
  const int node = blockIdx.x * 4 + (threadIdx.x >> 6);
  const int lane = threadIdx.x & 63;
  const int c0 = lane * 8;
  f32x8 acc = fp8x8_to_f32(*reinterpret_cast<const u32x2*>(xq + (size_t)node * DD + c0));
  f32x8 acc2 = {};
  const int p1 = rowptr[node + 1];
  int p = rowptr[node];
  for (; p + 1 < p1; p += 2) {
    const int s0 = csrc[p];
    const int s1 = csrc[p + 1];
    u32x2 r0 = *reinterpret_cast<const u32x2*>(xq + (size_t)s0 * DD + c0);
    u32x2 r1 = *reinterpret_cast<const u32x2*>(xq + (size_t)s1 * DD + c0);
    acc += fp8x8_to_f32(r0);
    acc2 += fp8x8_to_f32(r1);
  }
  if (p < p1) {
    const int s0 = csrc[p];
    acc += fp8x8_to_f32(*reinterpret_cast<const u32x2*>(xq + (size_t)s0 * DD + c0));
  }
  acc += acc2;
  *reinterpret_cast<bf16x8*>(xout + (size_t)node * DD + c0) =
      __builtin_convertvector(acc, bf16x8);
}

// ============ boundary agg: xact[v] = bf16( act(z[v]) + sum_u act(z[u]) ) ============
__global__ __launch_bounds__(256) void agg_act_k(const unsigned char* __restrict__ z,
                                                 const float* __restrict__ scsh,
                                                 const int* __restrict__ rowptr,
                                                 const int* __restrict__ csrc,
                                                 unsigned short* __restrict__ xout) {
  const int node = blockIdx.x * 4 + (threadIdx.x >> 6);
  const int lane = threadIdx.x & 63;
  const int c0 = lane * 8;
  f32x4 sca = *reinterpret_cast<const f32x4*>(scsh + c0);
  f32x4 scb = *reinterpret_cast<const f32x4*>(scsh + c0 + 4);
  f32x4 sha = *reinterpret_cast<const f32x4*>(scsh + DD + c0);
  f32x4 shb = *reinterpret_cast<const f32x4*>(scsh + DD + c0 + 4);
#define ACT8(dst, uv)                                                    \
  {                                                                      \
    f32x8 f_ = fp8x8_to_f32(uv);                                         \
    _Pragma("unroll") for (int q = 0; q < 4; ++q) {                      \
      dst[q]     += fmaxf(f_[q]     * sca[q] + sha[q], 0.f);             \
      dst[q + 4] += fmaxf(f_[q + 4] * scb[q] + shb[q], 0.f);             \
    }                                                                    \
  }
  f32x8 acc = {}, acc2 = {};
  u32x2 sv = *reinterpret_cast<const u32x2*>(z + (size_t)node * DD + c0);
  ACT8(acc, sv)
  const int p1 = rowptr[node + 1];
  int p = rowptr[node];
  for (; p + 1 < p1; p += 2) {
    const int s0 = csrc[p];
    const int s1 = csrc[p + 1];
    u32x2 r0 = *reinterpret_cast<const u32x2*>(z + (size_t)s0 * DD + c0);
    u32x2 r1 = *reinterpret_cast<const u32x2*>(z + (size_t)s1 * DD + c0);
    ACT8(acc, r0)
    ACT8(acc2, r1)
  }
  if (p < p1) {
    const int s0 = csrc[p];
    u32x2 r0 = *reinterpret_cast<const u32x2*>(z + (size_t)s0 * DD + c0);
    ACT8(acc, r0)
  }
  acc += acc2;
#undef ACT8
  *reinterpret_cast<bf16x8*>(xout + (size_t)node * DD + c0) =
      __builtin_convertvector(acc, bf16x8);
}

// ============ colsum of act(z) over real rows (precomputed scsh) ============
__global__ __launch_bounds__(256) void colsum_act_k(const unsigned char* __restrict__ z,
                                                    const float* __restrict__ scsh,
                                                    float* __restrict__ cs) {
  __shared__ float red[4][DD];
  const int g = threadIdx.x >> 6;
  const int lane = threadIdx.x & 63;
  const int c0 = lane * 8;
  f32x4 sca = *reinterpret_cast<const f32x4*>(scsh + c0);
  f32x4 scb = *reinterpret_cast<const f32x4*>(scsh + c0 + 4);
  f32x4 sha = *reinterpret_cast<const f32x4*>(scsh + DD + c0);
  f32x4 shb = *reinterpret_cast<const f32x4*>(scsh + DD + c0 + 4);
  f32x8 acc = {};
  for (int rr = g; rr < 128; rr += 4) {
    const int row = blockIdx.x * 128 + rr;
    if (row < NN) {
      u32x2 rv = *reinterpret_cast<const u32x2*>(z + (size_t)row * DD + c0);
      f32x8 f = fp8x8_to_f32(rv);
#pragma unroll
      for (int q = 0; q < 4; ++q) {
        acc[q]     += fmaxf(f[q]     * sca[q] + sha[q], 0.f);
        acc[q + 4] += fmaxf(f[q + 4] * scb[q] + shb[q], 0.f);
      }
    }
  }
#pragma unroll
  for (int q = 0; q < 8; ++q) red[g][c0 + q] = acc[q];
  __syncthreads();
  for (int cc = threadIdx.x; cc < DD; cc += 256) {
    const float s = red[0][cc] + red[1][cc] + red[2][cc] + red[3][cc];
    atomicAdd(&cs[cc], s);
  }
}

// ============ fused GEMM v3 + last-block BN finalize ============
// 128x128, ring-2, 64KB LDS, 2 blocks/CU. Last block (done-counter) computes scsh
// from the completed stats atomics (read back via atomics = device-coherent).
__global__ __launch_bounds__(512, 4) void gemmf_k(
    const unsigned short* __restrict__ A, const unsigned short* __restrict__ B,
    unsigned char* __restrict__ Z, float* __restrict__ stats,
    const float* __restrict__ degp1, const float* __restrict__ cvec,
    const float* __restrict__ gamma, const float* __restrict__ beta,
    float* __restrict__ scsh, int* __restrict__ done) {
  __shared__ unsigned short sm[32768];  // 64KB: [A0][A1][B0][B1]; C overlays A0+A1
  __shared__ int amlast;
  const int tid = threadIdx.x;
  const int lane = tid & 63;
  const int w = tid >> 6;
  const int rg = (w >> 2) * 64;
  const int cg = (w & 3) * 32;
  const int fr = lane & 15;
  const int fg = lane >> 4;
  const int sx = fr & 7;
  const int bid = blockIdx.x;
  const int swb = (bid & 7) * 196 + (bid >> 3);  // 1568 = 8*196, bijective XCD swizzle
  const int brow = (swb >> 2) * 128;
  const int bcol = (swb & 3) * 128;
  const char* Ab = (const char*)A + (size_t)brow * 1024;
  const char* Bb = (const char*)B + (size_t)bcol * 1024;
  const int srow = tid >> 3;
  const int sce = (tid & 7) * 8;
  const int sswz = (((tid & 7) ^ (srow & 7))) * 16;

  f32x4 acc[4][2] = {};

#define STG(t, b)                                                                    \
  _Pragma("unroll") for (int i = 0; i < 2; ++i) {                                    \
    gload16(Ab + (size_t)(i * 64 + srow) * 1024 + (t) * 128 + sswz,                  \
            &sm[(b) * 8192 + (i * 64 + srow) * 64 + sce]);                           \
    gload16(Bb + (size_t)(i * 64 + srow) * 1024 + (t) * 128 + sswz,                  \
            &sm[16384 + (b) * 8192 + (i * 64 + srow) * 64 + sce]);                   \
  }

  STG(0, 0)

#pragma unroll
  for (int kt = 0; kt < 8; ++kt) {
    asm volatile("s_waitcnt vmcnt(0)" ::: "memory");
    __builtin_amdgcn_s_barrier();
    if (kt < 7) STG(kt + 1, (kt + 1) & 1)
    const unsigned short* la = &sm[(kt & 1) * 8192];
    const unsigned short* lb = &sm[16384 + (kt & 1) * 8192];
    bf16x8 av[2][4], bv[2][2];
#pragma unroll
    for (int kk = 0; kk < 2; ++kk) {
      const int so = ((kk * 4 + fg) ^ sx) * 8;
#pragma unroll
      for (int i = 0; i < 4; ++i)
        av[kk][i] = *reinterpret_cast<const bf16x8*>(&la[(rg + i * 16 + fr) * 64 + so]);
#pragma unroll
      for (int j = 0; j < 2; ++j)
        bv[kk][j] = *reinterpret_cast<const bf16x8*>(&lb[(cg + j * 16 + fr) * 64 + so]);
    }
    asm volatile("s_waitcnt lgkmcnt(0)" ::: "memory");
    __builtin_amdgcn_sched_barrier(0);
    __builtin_amdgcn_s_setprio(1);
#pragma unroll
    for (int kk = 0; kk < 2; ++kk)
#pragma unroll
      for (int i = 0; i < 4; ++i)
#pragma unroll
        for (int j = 0; j < 2; ++j)
          acc[i][j] = __builtin_amdgcn_mfma_f32_16x16x32_bf16(av[kk][i], bv[kk][j], acc[i][j], 0, 0, 0);
    __builtin_amdgcn_s_setprio(0);
  }
#undef STG

  if (cvec != nullptr) {
    float cj[2];
#pragma unroll
    for (int j = 0; j < 2; ++j) cj[j] = cvec[bcol + cg + j * 16 + fr];
#pragma unroll
    for (int i = 0; i < 4; ++i)
#pragma unroll
      for (int r = 0; r < 4; ++r) {
        const float dgv = degp1[brow + rg + i * 16 + fg * 4 + r];
#pragma unroll
        for (int j = 0; j < 2; ++j) acc[i][j][r] += dgv * cj[j];
      }
  }

#pragma unroll
  for (int j = 0; j < 2; ++j) {
    const int col = bcol + cg + j * 16 + fr;
    float s1 = 0.f, s2 = 0.f;
#pragma unroll
    for (int i = 0; i < 4; ++i)
#pragma unroll
      for (int r = 0; r < 4; ++r) {
        const float v = acc[i][j][r];
        s1 += v;
        s2 += v * v;
      }
    s1 += __shfl_down(s1, 32);
    s2 += __shfl_down(s2, 32);
    s1 += __shfl_down(s1, 16);
    s2 += __shfl_down(s2, 16);
    if (lane < 16) {
      atomicAdd(&stats[col], s1);
      atomicAdd(&stats[DD + col], s2);
    }
  }

  __builtin_amdgcn_s_barrier();  // all MFMA LDS reads complete before C overlay
  unsigned short* C = sm;
#pragma unroll
  for (int j = 0; j < 2; ++j)
#pragma unroll
    for (int i = 0; i < 4; ++i)
#pragma unroll
      for (int r = 0; r < 4; ++r) {
        const int row = rg + i * 16 + fg * 4 + r;
        const int col = cg + j * 16 + fr;
        __bf16 b = (__bf16)acc[i][j][r];
        C[row * 128 + (((col >> 3) ^ (row & 7)) << 3) + (col & 7)] =
            __builtin_bit_cast(unsigned short, b);
      }
  asm volatile("s_waitcnt lgkmcnt(0)" ::: "memory");
  __builtin_amdgcn_s_barrier();
  const int orow = tid >> 2;
  const int ox = orow & 7;
  const unsigned short* cr = &C[orow * 128];
  unsigned char* zg = Z + (size_t)(brow + orow) * DD + bcol;
#pragma unroll
  for (int i = 0; i < 4; ++i) {
    const int s = (tid & 3) * 4 + ((i + tid) & 3);
    u16x8 cv = *reinterpret_cast<const u16x8*>(cr + (s ^ ox) * 8);
    f32x8 cf = __builtin_convertvector(__builtin_bit_cast(bf16x8, cv), f32x8);
    *reinterpret_cast<u32x2*>(zg + s * 8) = f32x8_to_fp8(cf);
  }

  // ---- last-block BN finalize (replaces bnfin_k dispatch) ----
  __threadfence();  // my stats atomics + z writes ordered before counter bump
  if (tid == 0) amlast = (atomicAdd(done, 1) == gridDim.x - 1);
  __syncthreads();
  if (amlast && tid < DD) {
    const float inv = 1.0f / (float)NN;
    const float s1 = atomicAdd(&stats[tid], 0.0f);        // coherent read-back
    const float s2 = atomicAdd(&stats[DD + tid], 0.0f);
    const float mu = s1 * inv;
    const float var = s2 * inv - mu * mu;
    const float sc = rsqrtf(var + 1e-5f) * gamma[tid];
    scsh[tid] = sc;
    scsh[DD + tid] = beta[tid] - mu * sc;
  }
}

// ============ final outputs: one wave per output element ============
__global__ __launch_bounds__(256) void out_k(const float* __restrict__ cs3,
                                             const float* __restrict__ cs2,
                                             const float* __restrict__ W2all,
                                             const float* __restrict__ b2all,
                                             float* __restrict__ out) {
  const int o = blockIdx.x * 4 + (threadIdx.x >> 6);  // 0..1023
  const int lane = threadIdx.x & 63;
  const int layer = (o < DD) ? 3 : 2;
  const int n = o & (DD - 1);
  const float* cs = (o < DD) ? cs3 : cs2;
  const float* row = W2all + (size_t)layer * DD * DD + (size_t)n * DD + lane * 8;
  f32x4 w0 = *reinterpret_cast<const f32x4*>(row);
  f32x4 w1 = *reinterpret_cast<const f32x4*>(row + 4);
  f32x4 c0 = *reinterpret_cast<const f32x4*>(cs + lane * 8);
  f32x4 c1 = *reinterpret_cast<const f32x4*>(cs + lane * 8 + 4);
  float s = w0[0]*c0[0] + w0[1]*c0[1] + w0[2]*c0[2] + w0[3]*c0[3]
          + w1[0]*c1[0] + w1[1]*c1[1] + w1[2]*c1[2] + w1[3]*c1[3];
#pragma unroll
  for (int d = 32; d > 0; d >>= 1) s += __shfl_down(s, d);
  if (lane == 0) out[o] = s / (float)NN + b2all[layer * DD + n];
}

extern "C" void kernel_launch(void* const* d_in, const int* in_sizes, int n_in,
                              void* d_out, int out_size, void* d_ws, size_t ws_size,
                              hipStream_t stream) {
  const float* x     = (const float*)d_in[0];
  const float* W1    = (const float*)d_in[1];
  // d_in[2] = b1: cancels exactly in training-mode BatchNorm -> unused
  const float* gamma = (const float*)d_in[3];
  const float* beta  = (const float*)d_in[4];
  const float* W2    = (const float*)d_in[5];
  const float* b2    = (const float*)d_in[6];
  const int*   src   = (const int*)d_in[7];
  const int*   dst   = (const int*)d_in[8];
  float* out = (float*)d_out;

  char* ws = (char*)d_ws;
  unsigned short* xact   = (unsigned short*)(ws);                 // 51,380,224
  unsigned char*  z      = (unsigned char*)(ws + 51380224);       // 25,690,112
  unsigned char*  xq     = (unsigned char*)(ws + 77070336);       // 25,600,000
  unsigned short* wb1    = (unsigned short*)(ws + 102670336);     // 524,288
  unsigned short* wf     = (unsigned short*)(ws + 103194624);     // 1,572,864
  float*          w2t    = (float*)(ws + 104767488);              // 3,145,728
  float*          cvec   = (float*)(ws + 107913216);              // 6,144
  float*          cs2    = (float*)(ws + 107921408);              // 2,048
  float*          cs3    = (float*)(ws + 107923456);              // 2,048
  float*          statsL = (float*)(ws + 107925504);              // 16,384 (4 x 2 x 512)
  float*          scshL  = (float*)(ws + 107941888);              // 16,384 (4 x 2 x 512)
  int*            doneL  = (int*)(ws + 107958272);                // 16
  float*          degp1  = (float*)(ws + 107958784);              // 200,704
  int*            rowptr = (int*)(ws + 108159488);                // 200,192
  int*            cursor = (int*)(ws + 108359680);                // 200,192
  int*            csrc   = (int*)(ws + 108559872);                // 600,000

  // cursor must be zero BEFORE prep1's count (separate dispatch: no same-grid race)
  hipMemsetAsync(cursor, 0, NN * sizeof(int), stream);
  prep1_k<<<13259, 256, 0, stream>>>(x, W1, dst, xq, wb1, cursor, xact, statsL, cs2, cs3, doneL);
  scan_k<<<1, 1024, 0, stream>>>(cursor, rowptr, cursor);
  prep2_k<<<778, 256, 0, stream>>>(src, dst, cursor, csrc, W2, w2t);
  prep3_k<<<247, 256, 0, stream>>>(W1, w2t, wf, b2, cvec, rowptr, degp1);

  // --- layer 0 ---
  agg_x_k<<<NN / 4, 256, 0, stream>>>(xq, rowptr, csrc, xact);
  gemmf_k<<<1568, 512, 0, stream>>>(xact, wb1, z, statsL, degp1, nullptr,
                                    gamma, beta, scshL, doneL);

  // --- boundaries l -> l+1 (fused W1_{l+1} @ W2_l); BN finalize inside gemmf ---
  for (int l = 0; l < 3; ++l) {
    agg_act_k<<<NN / 4, 256, 0, stream>>>(z, scshL + (size_t)l * 2 * DD, rowptr, csrc, xact);
    if (l == 2)
      colsum_act_k<<<392, 256, 0, stream>>>(z, scshL + (size_t)2 * 2 * DD, cs2);
    gemmf_k<<<1568, 512, 0, stream>>>(xact, wf + (size_t)l * DD * DD, z,
                                      statsL + (size_t)(l + 1) * 2 * DD, degp1,
                                      cvec + l * DD,
                                      gamma + (size_t)(l + 1) * DD,
                                      beta + (size_t)(l + 1) * DD,
                                      scshL + (size_t)(l + 1) * 2 * DD, doneL + (l + 1));
  }

  colsum_act_k<<<392, 256, 0, stream>>>(z, scshL + (size_t)3 * 2 * DD, cs3);
  out_k<<<256, 256, 0, stream>>>(cs3, cs2, W2, b2, out);
}

// Round 15
// 469.037 us; speedup vs baseline: 4.2820x; 4.2820x over previous
//
#include <hip/hip_runtime.h>

#define NN 50000
#define MPAD 50176  // 392 * 128
#define DD 512
#define NE 150000

typedef float f32x2 __attribute__((ext_vector_type(2)));
typedef float f32x4 __attribute__((ext_vector_type(4)));
typedef float f32x8 __attribute__((ext_vector_type(8)));
typedef __bf16 bf16x8 __attribute__((ext_vector_type(8)));
typedef unsigned short u16x8 __attribute__((ext_vector_type(8)));
typedef unsigned int u32x2 __attribute__((ext_vector_type(2)));

__device__ __forceinline__ void gload16(const void* g, void* l) {
  __builtin_amdgcn_global_load_lds((const __attribute__((address_space(1))) void*)g,
                                   (__attribute__((address_space(3))) void*)l, 16, 0, 0);
}

// ---- fp8 e4m3 pack/unpack (storage-only quantization) ----
__device__ __forceinline__ u32x2 f32x8_to_fp8(f32x8 v) {
  int t0 = __builtin_amdgcn_cvt_pk_fp8_f32(v[0], v[1], 0, false);
  t0 = __builtin_amdgcn_cvt_pk_fp8_f32(v[2], v[3], t0, true);
  int t1 = __builtin_amdgcn_cvt_pk_fp8_f32(v[4], v[5], 0, false);
  t1 = __builtin_amdgcn_cvt_pk_fp8_f32(v[6], v[7], t1, true);
  u32x2 r;
  r[0] = (unsigned)t0;
  r[1] = (unsigned)t1;
  return r;
}
__device__ __forceinline__ f32x8 fp8x8_to_f32(u32x2 u) {
  f32x2 a = __builtin_amdgcn_cvt_pk_f32_fp8((int)u[0], false);
  f32x2 b = __builtin_amdgcn_cvt_pk_f32_fp8((int)u[0], true);
  f32x2 c = __builtin_amdgcn_cvt_pk_f32_fp8((int)u[1], false);
  f32x2 d = __builtin_amdgcn_cvt_pk_f32_fp8((int)u[1], true);
  f32x8 v;
  v[0]=a[0]; v[1]=a[1]; v[2]=b[0]; v[3]=b[1]; v[4]=c[0]; v[5]=c[1]; v[6]=d[0]; v[7]=d[1];
  return v;
}

// ============ prep1: x->fp8 (12500) | W1_0->bf16 (128) | edge count (586) |
//              xact pad zero (44) | statsL/cs zero (1).  Grid = 13259.
__global__ __launch_bounds__(256) void prep1_k(
    const float* __restrict__ x, const float* __restrict__ W1,
    const int* __restrict__ dst, unsigned char* __restrict__ xq,
    unsigned short* __restrict__ wb1, int* __restrict__ cnt,
    unsigned short* __restrict__ xact, float* __restrict__ statsL,
    float* __restrict__ cs2, float* __restrict__ cs3) {
  const int b = blockIdx.x;
  const int tid = threadIdx.x;
  if (b < 12500) {  // x f32 -> fp8
    const size_t i = ((size_t)b * 256 + tid) * 8;
    const f32x4* g = reinterpret_cast<const f32x4*>(x + i);
    f32x4 a = g[0], c = g[1];
    f32x8 v;
    v[0]=a[0]; v[1]=a[1]; v[2]=a[2]; v[3]=a[3]; v[4]=c[0]; v[5]=c[1]; v[6]=c[2]; v[7]=c[3];
    *reinterpret_cast<u32x2*>(xq + i) = f32x8_to_fp8(v);
  } else if (b < 12628) {  // W1 layer 0 -> bf16
    const size_t i = ((size_t)(b - 12500) * 256 + tid) * 8;
    const f32x4* g = reinterpret_cast<const f32x4*>(W1 + i);
    f32x4 a = g[0], c = g[1];
    f32x8 v;
    v[0]=a[0]; v[1]=a[1]; v[2]=a[2]; v[3]=a[3]; v[4]=c[0]; v[5]=c[1]; v[6]=c[2]; v[7]=c[3];
    *reinterpret_cast<bf16x8*>(wb1 + i) = __builtin_convertvector(v, bf16x8);
  } else if (b < 13214) {  // in-degree count (cursor pre-zeroed by memset)
    const int e = (b - 12628) * 256 + tid;
    if (e < NE) atomicAdd(&cnt[dst[e]], 1);
  } else if (b < 13258) {  // xact pad rows -> 0
    const int i = (b - 13214) * 256 + tid;
    u16x8 zz = {};
    *reinterpret_cast<u16x8*>(xact + (size_t)NN * DD + (size_t)i * 8) = zz;
  } else {  // zero statsL (4 layers) + colsum accumulators
    for (int i = tid; i < 8 * DD; i += 256) statsL[i] = 0.f;
    for (int i = tid; i < DD; i += 256) {
      cs2[i] = 0.f;
      cs3[i] = 0.f;
    }
  }
}

// ============ single-block exclusive scan ============
__global__ __launch_bounds__(1024) void scan_k(const int* __restrict__ cnt,
                                               int* __restrict__ rowptr,
                                               int* __restrict__ cursor) {
  __shared__ int wsum[16];
  __shared__ int base_s;
  if (threadIdx.x == 0) base_s = 0;
  __syncthreads();
  const int lane = threadIdx.x & 63;
  const int wid = threadIdx.x >> 6;
  for (int c0 = 0; c0 < NN; c0 += 1024) {
    const int i = c0 + threadIdx.x;
    const int v = (i < NN) ? cnt[i] : 0;
    int incl = v;
#pragma unroll
    for (int d = 1; d < 64; d <<= 1) {
      int t = __shfl_up(incl, d);
      if (lane >= d) incl += t;
    }
    if (lane == 63) wsum[wid] = incl;
    __syncthreads();
    if (wid == 0 && lane < 16) {
      int wv = wsum[lane];
#pragma unroll
      for (int d = 1; d < 16; d <<= 1) {
        int t = __shfl_up(wv, d);
        if (lane >= d) wv += t;
      }
      wsum[lane] = wv;
    }
    __syncthreads();
    const int waveoff = wid ? wsum[wid - 1] : 0;
    const int excl = base_s + waveoff + incl - v;
    if (i < NN) {
      rowptr[i] = excl;
      cursor[i] = excl;
    }
    __syncthreads();
    if (threadIdx.x == 0) base_s += wsum[15];
    __syncthreads();
  }
  if (threadIdx.x == 0) rowptr[NN] = base_s;
}

// ============ prep2: CSR fill (586) | W2 transpose (192).  Grid = 778. ============
__global__ __launch_bounds__(256) void prep2_k(
    const int* __restrict__ src, const int* __restrict__ dst,
    int* __restrict__ cursor, int* __restrict__ csrc,
    const float* __restrict__ W2, float* __restrict__ W2T) {
  __shared__ float t[64][65];
  const int b = blockIdx.x;
  const int tid = threadIdx.x;
  if (b < 586) {
    const int e = b * 256 + tid;
    if (e < NE) {
      const int pos = atomicAdd(&cursor[dst[e]], 1);
      csrc[pos] = src[e];
    }
  } else {
    const int q = b - 586;
    const int l = q >> 6;
    const int rem = q & 63;
    const int a0 = (rem >> 3) * 64;
    const int b0 = (rem & 7) * 64;
    const float* sp = W2 + (size_t)l * DD * DD;
    float* dp = W2T + (size_t)l * DD * DD;
#pragma unroll
    for (int k = 0; k < 16; ++k) {
      const int idx = k * 256 + tid;
      const int r = idx >> 6, c = idx & 63;
      t[r][c] = sp[(size_t)(a0 + r) * DD + b0 + c];
    }
    __syncthreads();
#pragma unroll
    for (int k = 0; k < 16; ++k) {
      const int idx = k * 256 + tid;
      const int r = idx >> 6, c = idx & 63;
      dp[(size_t)(b0 + r) * DD + a0 + c] = t[c][r];
    }
  }
}

// ============ prep3: Wf (48) | cvec (3) | degp1 (196).  Grid = 247. ============
__global__ __launch_bounds__(256) void prep3_k(
    const float* __restrict__ W1all, const float* __restrict__ W2T,
    unsigned short* __restrict__ WF, const float* __restrict__ b2all,
    float* __restrict__ cvec, const int* __restrict__ rowptr,
    float* __restrict__ degp1) {
  __shared__ char pl[36864];
  const int b = blockIdx.x;
  const int tid = threadIdx.x;
  if (b < 48) {
    constexpr int LDK = 72;
    unsigned short* lA = (unsigned short*)pl;
    unsigned short* lB = (unsigned short*)(pl + 18432);
    const int l = b >> 4;
    const int rem = b & 15;
    const int brow = (rem >> 2) * 128;
    const int bcol = (rem & 3) * 128;
    const float* A = W1all + (size_t)(l + 1) * DD * DD;
    const float* Bt = W2T + (size_t)l * DD * DD;
    unsigned short* out = WF + (size_t)l * DD * DD;
    const int lane = tid & 63;
    const int w = tid >> 6;
    const int wr = (w >> 1) * 64;
    const int wc = (w & 1) * 64;
    const int fr = lane & 15;
    const int fg = lane >> 4;
    f32x4 acc[4][4] = {};
    const int srow = tid >> 3;
    const int scol = (tid & 7) * 8;
    for (int kt = 0; kt < 8; ++kt) {
      const int k0 = kt * 64 + scol;
      __syncthreads();
#pragma unroll
      for (int p = 0; p < 4; ++p) {
        const int r = srow + 32 * p;
        {
          const f32x4* g = reinterpret_cast<const f32x4*>(A + (size_t)(brow + r) * DD + k0);
          f32x4 v0 = g[0], v1 = g[1];
          f32x8 vf;
          vf[0]=v0[0]; vf[1]=v0[1]; vf[2]=v0[2]; vf[3]=v0[3];
          vf[4]=v1[0]; vf[5]=v1[1]; vf[6]=v1[2]; vf[7]=v1[3];
          *reinterpret_cast<bf16x8*>(&lA[r * LDK + scol]) = __builtin_convertvector(vf, bf16x8);
        }
        {
          const f32x4* g = reinterpret_cast<const f32x4*>(Bt + (size_t)(bcol + r) * DD + k0);
          f32x4 v0 = g[0], v1 = g[1];
          f32x8 vf;
          vf[0]=v0[0]; vf[1]=v0[1]; vf[2]=v0[2]; vf[3]=v0[3];
          vf[4]=v1[0]; vf[5]=v1[1]; vf[6]=v1[2]; vf[7]=v1[3];
          *reinterpret_cast<bf16x8*>(&lB[r * LDK + scol]) = __builtin_convertvector(vf, bf16x8);
        }
      }
      __syncthreads();
#pragma unroll
      for (int kk = 0; kk < 2; ++kk) {
        bf16x8 av[4], bv[4];
#pragma unroll
        for (int i = 0; i < 4; ++i)
          av[i] = *reinterpret_cast<const bf16x8*>(&lA[(wr + i * 16 + fr) * LDK + kk * 32 + fg * 8]);
#pragma unroll
        for (int j = 0; j < 4; ++j)
          bv[j] = *reinterpret_cast<const bf16x8*>(&lB[(wc + j * 16 + fr) * LDK + kk * 32 + fg * 8]);
#pragma unroll
        for (int i = 0; i < 4; ++i)
#pragma unroll
          for (int j = 0; j < 4; ++j)
            acc[i][j] = __builtin_amdgcn_mfma_f32_16x16x32_bf16(av[i], bv[j], acc[i][j], 0, 0, 0);
      }
    }
#pragma unroll
    for (int j = 0; j < 4; ++j) {
      const int col = bcol + wc + j * 16 + fr;
#pragma unroll
      for (int i = 0; i < 4; ++i) {
        const int rb = brow + wr + i * 16 + fg * 4;
#pragma unroll
        for (int r = 0; r < 4; ++r) {
          __bf16 bb = (__bf16)acc[i][j][r];
          out[(size_t)(rb + r) * DD + col] = __builtin_bit_cast(unsigned short, bb);
        }
      }
    }
  } else if (b < 51) {
    const int l = b - 48;
    float* bb = (float*)pl;
    bb[tid] = b2all[(size_t)l * DD + tid];
    bb[tid + 256] = b2all[(size_t)l * DD + tid + 256];
    __syncthreads();
#pragma unroll
    for (int rep = 0; rep < 2; ++rep) {
      const int n = tid + rep * 256;
      const float* row = W1all + (size_t)(l + 1) * DD * DD + (size_t)n * DD;
      float s = 0.f;
      for (int a = 0; a < DD; a += 4) {
        f32x4 v = *reinterpret_cast<const f32x4*>(row + a);
        s += v[0] * bb[a] + v[1] * bb[a + 1] + v[2] * bb[a + 2] + v[3] * bb[a + 3];
      }
      cvec[l * DD + n] = s;
    }
  } else {
    const int i = (b - 51) * 256 + tid;
    if (i < MPAD) degp1[i] = (i < NN) ? (float)(1 + rowptr[i + 1] - rowptr[i]) : 0.f;
  }
}

// ============ BN finalize per layer: statsL(l) -> scshL(l) ============
__global__ void bnfin_k(const float* __restrict__ stats, const float* __restrict__ gamma,
                        const float* __restrict__ beta, float* __restrict__ scsh) {
  const int n = threadIdx.x;
  const float inv = 1.0f / (float)NN;
  const float mu = stats[n] * inv;
  const float var = stats[DD + n] * inv - mu * mu;
  const float sc = rsqrtf(var + 1e-5f) * gamma[n];
  scsh[n] = sc;
  scsh[DD + n] = beta[n] - mu * sc;
}

// ============ layer-0 aggregation from fp8 x (unroll-2) ============
__global__ __launch_bounds__(256) void agg_x_k(const unsigned char* __restrict__ xq,
                                               const int* __restrict__ rowptr,
                                               const int* __restrict__ csrc,
                                               unsigned short* __restrict__ xout) {
  const int node = blockIdx.x * 4 + (threadIdx.x >> 6);
  const int lane = threadIdx.x & 63;
  const int c0 = lane * 8;
  f32x8 acc = fp8x8_to_f32(*reinterpret_cast<const u32x2*>(xq + (size_t)node * DD + c0));
  f32x8 acc2 = {};
  const int p1 = rowptr[node + 1];
  int p = rowptr[node];
  for (; p + 1 < p1; p += 2) {
    const int s0 = csrc[p];
    const int s1 = csrc[p + 1];
    u32x2 r0 = *reinterpret_cast<const u32x2*>(xq + (size_t)s0 * DD + c0);
    u32x2 r1 = *reinterpret_cast<const u32x2*>(xq + (size_t)s1 * DD + c0);
    acc += fp8x8_to_f32(r0);
    acc2 += fp8x8_to_f32(r1);
  }
  if (p < p1) {
    const int s0 = csrc[p];
    acc += fp8x8_to_f32(*reinterpret_cast<const u32x2*>(xq + (size_t)s0 * DD + c0));
  }
  acc += acc2;
  *reinterpret_cast<bf16x8*>(xout + (size_t)node * DD + c0) =
      __builtin_convertvector(acc, bf16x8);
}

// ============ boundary agg: xact[v] = bf16( act(z[v]) + sum_u act(z[u]) ) ============
__global__ __launch_bounds__(256) void agg_act_k(const unsigned char* __restrict__ z,
                                                 const float* __restrict__ scsh,
                                                 const int* __restrict__ rowptr,
                                                 const int* __restrict__ csrc,
                                                 unsigned short* __restrict__ xout) {
  const int node = blockIdx.x * 4 + (threadIdx.x >> 6);
  const int lane = threadIdx.x & 63;
  const int c0 = lane * 8;
  f32x4 sca = *reinterpret_cast<const f32x4*>(scsh + c0);
  f32x4 scb = *reinterpret_cast<const f32x4*>(scsh + c0 + 4);
  f32x4 sha = *reinterpret_cast<const f32x4*>(scsh + DD + c0);
  f32x4 shb = *reinterpret_cast<const f32x4*>(scsh + DD + c0 + 4);
#define ACT8(dst, uv)                                                    \
  {                                                                      \
    f32x8 f_ = fp8x8_to_f32(uv);                                         \
    _Pragma("unroll") for (int q = 0; q < 4; ++q) {                      \
      dst[q]     += fmaxf(f_[q]     * sca[q] + sha[q], 0.f);             \
      dst[q + 4] += fmaxf(f_[q + 4] * scb[q] + shb[q], 0.f);             \
    }                                                                    \
  }
  f32x8 acc = {}, acc2 = {};
  u32x2 sv = *reinterpret_cast<const u32x2*>(z + (size_t)node * DD + c0);
  ACT8(acc, sv)
  const int p1 = rowptr[node + 1];
  int p = rowptr[node];
  for (; p + 1 < p1; p += 2) {
    const int s0 = csrc[p];
    const int s1 = csrc[p + 1];
    u32x2 r0 = *reinterpret_cast<const u32x2*>(z + (size_t)s0 * DD + c0);
    u32x2 r1 = *reinterpret_cast<const u32x2*>(z + (size_t)s1 * DD + c0);
    ACT8(acc, r0)
    ACT8(acc2, r1)
  }
  if (p < p1) {
    const int s0 = csrc[p];
    u32x2 r0 = *reinterpret_cast<const u32x2*>(z + (size_t)s0 * DD + c0);
    ACT8(acc, r0)
  }
  acc += acc2;
#undef ACT8
  *reinterpret_cast<bf16x8*>(xout + (size_t)node * DD + c0) =
      __builtin_convertvector(acc, bf16x8);
}

// ============ colsum of act(z) over real rows (precomputed scsh) ============
__global__ __launch_bounds__(256) void colsum_act_k(const unsigned char* __restrict__ z,
                                                    const float* __restrict__ scsh,
                                                    float* __restrict__ cs) {
  __shared__ float red[4][DD];
  const int g = threadIdx.x >> 6;
  const int lane = threadIdx.x & 63;
  const int c0 = lane * 8;
  f32x4 sca = *reinterpret_cast<const f32x4*>(scsh + c0);
  f32x4 scb = *reinterpret_cast<const f32x4*>(scsh + c0 + 4);
  f32x4 sha = *reinterpret_cast<const f32x4*>(scsh + DD + c0);
  f32x4 shb = *reinterpret_cast<const f32x4*>(scsh + DD + c0 + 4);
  f32x8 acc = {};
  for (int rr = g; rr < 128; rr += 4) {
    const int row = blockIdx.x * 128 + rr;
    if (row < NN) {
      u32x2 rv = *reinterpret_cast<const u32x2*>(z + (size_t)row * DD + c0);
      f32x8 f = fp8x8_to_f32(rv);
#pragma unroll
      for (int q = 0; q < 4; ++q) {
        acc[q]     += fmaxf(f[q]     * sca[q] + sha[q], 0.f);
        acc[q + 4] += fmaxf(f[q + 4] * scb[q] + shb[q], 0.f);
      }
    }
  }
#pragma unroll
  for (int q = 0; q < 8; ++q) red[g][c0 + q] = acc[q];
  __syncthreads();
  for (int cc = threadIdx.x; cc < DD; cc += 256) {
    const float s = red[0][cc] + red[1][cc] + red[2][cc] + red[3][cc];
    atomicAdd(&cs[cc], s);
  }
}

// ============ fused GEMM v3: 128x128, ring-2, 64KB LDS, 2 blocks/CU ============
__global__ __launch_bounds__(512, 4) void gemmf_k(
    const unsigned short* __restrict__ A, const unsigned short* __restrict__ B,
    unsigned char* __restrict__ Z, float* __restrict__ stats,
    const float* __restrict__ degp1, const float* __restrict__ cvec) {
  __shared__ unsigned short sm[32768];  // 64KB: [A0][A1][B0][B1]; C overlays A0+A1
  const int tid = threadIdx.x;
  const int lane = tid & 63;
  const int w = tid >> 6;
  const int rg = (w >> 2) * 64;
  const int cg = (w & 3) * 32;
  const int fr = lane & 15;
  const int fg = lane >> 4;
  const int sx = fr & 7;
  const int bid = blockIdx.x;
  const int swb = (bid & 7) * 196 + (bid >> 3);  // 1568 = 8*196, bijective XCD swizzle
  const int brow = (swb >> 2) * 128;
  const int bcol = (swb & 3) * 128;
  const char* Ab = (const char*)A + (size_t)brow * 1024;
  const char* Bb = (const char*)B + (size_t)bcol * 1024;
  const int srow = tid >> 3;
  const int sce = (tid & 7) * 8;
  const int sswz = (((tid & 7) ^ (srow & 7))) * 16;

  f32x4 acc[4][2] = {};

#define STG(t, b)                                                                    \
  _Pragma("unroll") for (int i = 0; i < 2; ++i) {                                    \
    gload16(Ab + (size_t)(i * 64 + srow) * 1024 + (t) * 128 + sswz,                  \
            &sm[(b) * 8192 + (i * 64 + srow) * 64 + sce]);                           \
    gload16(Bb + (size_t)(i * 64 + srow) * 1024 + (t) * 128 + sswz,                  \
            &sm[16384 + (b) * 8192 + (i * 64 + srow) * 64 + sce]);                   \
  }

  STG(0, 0)

#pragma unroll
  for (int kt = 0; kt < 8; ++kt) {
    asm volatile("s_waitcnt vmcnt(0)" ::: "memory");
    __builtin_amdgcn_s_barrier();
    if (kt < 7) STG(kt + 1, (kt + 1) & 1)
    const unsigned short* la = &sm[(kt & 1) * 8192];
    const unsigned short* lb = &sm[16384 + (kt & 1) * 8192];
    bf16x8 av[2][4], bv[2][2];
#pragma unroll
    for (int kk = 0; kk < 2; ++kk) {
      const int so = ((kk * 4 + fg) ^ sx) * 8;
#pragma unroll
      for (int i = 0; i < 4; ++i)
        av[kk][i] = *reinterpret_cast<const bf16x8*>(&la[(rg + i * 16 + fr) * 64 + so]);
#pragma unroll
      for (int j = 0; j < 2; ++j)
        bv[kk][j] = *reinterpret_cast<const bf16x8*>(&lb[(cg + j * 16 + fr) * 64 + so]);
    }
    asm volatile("s_waitcnt lgkmcnt(0)" ::: "memory");
    __builtin_amdgcn_sched_barrier(0);
    __builtin_amdgcn_s_setprio(1);
#pragma unroll
    for (int kk = 0; kk < 2; ++kk)
#pragma unroll
      for (int i = 0; i < 4; ++i)
#pragma unroll
        for (int j = 0; j < 2; ++j)
          acc[i][j] = __builtin_amdgcn_mfma_f32_16x16x32_bf16(av[kk][i], bv[kk][j], acc[i][j], 0, 0, 0);
    __builtin_amdgcn_s_setprio(0);
  }
#undef STG

  if (cvec != nullptr) {
    float cj[2];
#pragma unroll
    for (int j = 0; j < 2; ++j) cj[j] = cvec[bcol + cg + j * 16 + fr];
#pragma unroll
    for (int i = 0; i < 4; ++i)
#pragma unroll
      for (int r = 0; r < 4; ++r) {
        const float dgv = degp1[brow + rg + i * 16 + fg * 4 + r];
#pragma unroll
        for (int j = 0; j < 2; ++j) acc[i][j][r] += dgv * cj[j];
      }
  }

#pragma unroll
  for (int j = 0; j < 2; ++j) {
    const int col = bcol + cg + j * 16 + fr;
    float s1 = 0.f, s2 = 0.f;
#pragma unroll
    for (int i = 0; i < 4; ++i)
#pragma unroll
      for (int r = 0; r < 4; ++r) {
        const float v = acc[i][j][r];
        s1 += v;
        s2 += v * v;
      }
    s1 += __shfl_down(s1, 32);
    s2 += __shfl_down(s2, 32);
    s1 += __shfl_down(s1, 16);
    s2 += __shfl_down(s2, 16);
    if (lane < 16) {
      atomicAdd(&stats[col], s1);
      atomicAdd(&stats[DD + col], s2);
    }
  }

  __builtin_amdgcn_s_barrier();  // all MFMA LDS reads complete before C overlay
  unsigned short* C = sm;
#pragma unroll
  for (int j = 0; j < 2; ++j)
#pragma unroll
    for (int i = 0; i < 4; ++i)
#pragma unroll
      for (int r = 0; r < 4; ++r) {
        const int row = rg + i * 16 + fg * 4 + r;
        const int col = cg + j * 16 + fr;
        __bf16 b = (__bf16)acc[i][j][r];
        C[row * 128 + (((col >> 3) ^ (row & 7)) << 3) + (col & 7)] =
            __builtin_bit_cast(unsigned short, b);
      }
  asm volatile("s_waitcnt lgkmcnt(0)" ::: "memory");
  __builtin_amdgcn_s_barrier();
  const int orow = tid >> 2;
  const int ox = orow & 7;
  const unsigned short* cr = &C[orow * 128];
  unsigned char* zg = Z + (size_t)(brow + orow) * DD + bcol;
#pragma unroll
  for (int i = 0; i < 4; ++i) {
    const int s = (tid & 3) * 4 + ((i + tid) & 3);
    u16x8 cv = *reinterpret_cast<const u16x8*>(cr + (s ^ ox) * 8);
    f32x8 cf = __builtin_convertvector(__builtin_bit_cast(bf16x8, cv), f32x8);
    *reinterpret_cast<u32x2*>(zg + s * 8) = f32x8_to_fp8(cf);
  }
}

// ============ final outputs: one wave per output element ============
__global__ __launch_bounds__(256) void out_k(const float* __restrict__ cs3,
                                             const float* __restrict__ cs2,
                                             const float* __restrict__ W2all,
                                             const float* __restrict__ b2all,
                                             float* __restrict__ out) {
  const int o = blockIdx.x * 4 + (threadIdx.x >> 6);  // 0..1023
  const int lane = threadIdx.x & 63;
  const int layer = (o < DD) ? 3 : 2;
  const int n = o & (DD - 1);
  const float* cs = (o < DD) ? cs3 : cs2;
  const float* row = W2all + (size_t)layer * DD * DD + (size_t)n * DD + lane * 8;
  f32x4 w0 = *reinterpret_cast<const f32x4*>(row);
  f32x4 w1 = *reinterpret_cast<const f32x4*>(row + 4);
  f32x4 c0 = *reinterpret_cast<const f32x4*>(cs + lane * 8);
  f32x4 c1 = *reinterpret_cast<const f32x4*>(cs + lane * 8 + 4);
  float s = w0[0]*c0[0] + w0[1]*c0[1] + w0[2]*c0[2] + w0[3]*c0[3]
          + w1[0]*c1[0] + w1[1]*c1[1] + w1[2]*c1[2] + w1[3]*c1[3];
#pragma unroll
  for (int d = 32; d > 0; d >>= 1) s += __shfl_down(s, d);
  if (lane == 0) out[o] = s / (float)NN + b2all[layer * DD + n];
}

extern "C" void kernel_launch(void* const* d_in, const int* in_sizes, int n_in,
                              void* d_out, int out_size, void* d_ws, size_t ws_size,
                              hipStream_t stream) {
  const float* x     = (const float*)d_in[0];
  const float* W1    = (const float*)d_in[1];
  // d_in[2] = b1: cancels exactly in training-mode BatchNorm -> unused
  const float* gamma = (const float*)d_in[3];
  const float* beta  = (const float*)d_in[4];
  const float* W2    = (const float*)d_in[5];
  const float* b2    = (const float*)d_in[6];
  const int*   src   = (const int*)d_in[7];
  const int*   dst   = (const int*)d_in[8];
  float* out = (float*)d_out;

  char* ws = (char*)d_ws;
  unsigned short* xact   = (unsigned short*)(ws);                 // 51,380,224
  unsigned char*  z      = (unsigned char*)(ws + 51380224);       // 25,690,112
  unsigned char*  xq     = (unsigned char*)(ws + 77070336);       // 25,600,000
  unsigned short* wb1    = (unsigned short*)(ws + 102670336);     // 524,288
  unsigned short* wf     = (unsigned short*)(ws + 103194624);     // 1,572,864
  float*          w2t    = (float*)(ws + 104767488);              // 3,145,728
  float*          cvec   = (float*)(ws + 107913216);              // 6,144
  float*          cs2    = (float*)(ws + 107921408);              // 2,048
  float*          cs3    = (float*)(ws + 107923456);              // 2,048
  float*          statsL = (float*)(ws + 107925504);              // 16,384 (4 x 2 x 512)
  float*          scshL  = (float*)(ws + 107941888);              // 16,384 (4 x 2 x 512)
  float*          degp1  = (float*)(ws + 107958272);              // 200,704
  int*            rowptr = (int*)(ws + 108158976);                // 200,192
  int*            cursor = (int*)(ws + 108359168);                // 200,192
  int*            csrc   = (int*)(ws + 108559360);                // 600,000

  // cursor must be zero BEFORE prep1's count (separate dispatch: no same-grid race)
  hipMemsetAsync(cursor, 0, NN * sizeof(int), stream);
  prep1_k<<<13259, 256, 0, stream>>>(x, W1, dst, xq, wb1, cursor, xact, statsL, cs2, cs3);
  scan_k<<<1, 1024, 0, stream>>>(cursor, rowptr, cursor);
  prep2_k<<<778, 256, 0, stream>>>(src, dst, cursor, csrc, W2, w2t);
  prep3_k<<<247, 256, 0, stream>>>(W1, w2t, wf, b2, cvec, rowptr, degp1);

  // --- layer 0 ---
  agg_x_k<<<NN / 4, 256, 0, stream>>>(xq, rowptr, csrc, xact);
  gemmf_k<<<1568, 512, 0, stream>>>(xact, wb1, z, statsL, degp1, nullptr);
  bnfin_k<<<1, DD, 0, stream>>>(statsL, gamma, beta, scshL);

  // --- boundaries l -> l+1 (fused W1_{l+1} @ W2_l) ---
  for (int l = 0; l < 3; ++l) {
    agg_act_k<<<NN / 4, 256, 0, stream>>>(z, scshL + (size_t)l * 2 * DD, rowptr, csrc, xact);
    if (l == 2)
      colsum_act_k<<<392, 256, 0, stream>>>(z, scshL + (size_t)2 * 2 * DD, cs2);
    gemmf_k<<<1568, 512, 0, stream>>>(xact, wf + (size_t)l * DD * DD, z,
                                      statsL + (size_t)(l + 1) * 2 * DD, degp1,
                                      cvec + l * DD);
    bnfin_k<<<1, DD, 0, stream>>>(statsL + (size_t)(l + 1) * 2 * DD,
                                  gamma + (size_t)(l + 1) * DD, beta + (size_t)(l + 1) * DD,
                                  scshL + (size_t)(l + 1) * 2 * DD);
  }

  colsum_act_k<<<392, 256, 0, stream>>>(z, scshL + (size_t)3 * 2 * DD, cs3);
  out_k<<<256, 256, 0, stream>>>(cs3, cs2, W2, b2, out);
}